// Round 2
// baseline (269.278 us; speedup 1.0000x reference)
//
#include <hip/hip_runtime.h>
#include <stdint.h>
#include <stddef.h>

#define N_SENT 100000
#define N_TYPE 10000
#define NEDGE  640000
#define MAXDEG 1024   // LDS score cache per wave; Poisson(64) max deg ~115, 1024 is ultra-safe

__device__ __forceinline__ float bf2f(uint32_t lo16) {
    return __builtin_bit_cast(float, lo16 << 16);
}
__device__ __forceinline__ uint32_t f2bf(float f) {
    uint32_t u = __builtin_bit_cast(uint32_t, f);
    return (u + 0x7fffu + ((u >> 16) & 1u)) >> 16;
}

// ---- dtype detector: flag=1 if data is bf16 pairs, 0 if float32 ----
// bf16 N(0,1) data: low halfword exponent in [100,140] for every element.
// f32 data: low halfword bits are mantissa bits -> uniform exponent, ~16% hit rate.
__global__ void detect_k(const uint32_t* __restrict__ h, uint32_t* __restrict__ flag) {
    int lane = threadIdx.x;                 // 64 threads
    uint32_t u = h[lane];
    uint32_t e_lo = (u >> 7) & 0xffu;
    int ok = (e_lo >= 100u && e_lo <= 140u) ? 1 : 0;
    unsigned long long m = __ballot(ok);
    if (lane == 0) flag[0] = (__popcll(m) >= 48) ? 1u : 0u;
}

__global__ __launch_bounds__(256) void zero_u32_k(uint32_t* __restrict__ p, int n) {
    int i = blockIdx.x * 256 + threadIdx.x;
    if (i < n) p[i] = 0u;
}

// One wave per row. rows [0,N_SENT) -> s_src (w[:D]); [N_SENT,N_SENT+N_TYPE) -> s_dst (w[D:])
__global__ __launch_bounds__(256) void scores_k(const void* __restrict__ h_sent,
                                                const void* __restrict__ h_type,
                                                const void* __restrict__ attn_w,
                                                const uint32_t* __restrict__ flag,
                                                float* __restrict__ s_src,
                                                float* __restrict__ s_dst) {
    int wid  = (blockIdx.x * 256 + threadIdx.x) >> 6;
    int lane = threadIdx.x & 63;
    if (wid >= N_SENT + N_TYPE) return;
    bool isSrc = wid < N_SENT;
    int row  = isSrc ? wid : wid - N_SENT;
    int widx = isSrc ? lane : 64 + lane;
    const void* h = isSrc ? h_sent : h_type;
    float sum;
    if (flag[0]) {
        uint32_t hv = ((const uint32_t*)h)[(size_t)row * 64 + lane];
        uint32_t wv = ((const uint32_t*)attn_w)[widx];
        sum = bf2f(hv & 0xffffu) * bf2f(wv & 0xffffu)
            + bf2f(hv >> 16)     * bf2f(wv >> 16);
    } else {
        float2 hv = ((const float2*)h)[(size_t)row * 64 + lane];
        float2 wv = ((const float2*)attn_w)[widx];
        sum = hv.x * wv.x + hv.y * wv.y;
    }
#pragma unroll
    for (int off = 32; off; off >>= 1) sum += __shfl_xor(sum, off, 64);
    if (lane == 0) {
        if (isSrc) s_src[row] = sum;
        else       s_dst[row] = sum;
    }
}

// Per-dst in-degree
__global__ __launch_bounds__(256) void count_k(const int* __restrict__ dst,
                                               uint32_t* __restrict__ count) {
    int e = blockIdx.x * 256 + threadIdx.x;
    if (e >= NEDGE) return;
    atomicAdd(&count[dst[e]], 1u);
}

// Single-block exclusive scan: count[N_TYPE] -> offsets[N_TYPE+1]; count becomes cursor
__global__ __launch_bounds__(1024) void scan_k(uint32_t* __restrict__ count,
                                               uint32_t* __restrict__ offsets) {
    __shared__ uint32_t buf[1024];
    const int CH = 10;   // 1024*10 >= N_TYPE
    int t = threadIdx.x;
    int base = t * CH;
    uint32_t local[CH];
    uint32_t tsum = 0;
#pragma unroll
    for (int i = 0; i < CH; i++) {
        int idx = base + i;
        uint32_t c = (idx < N_TYPE) ? count[idx] : 0u;
        local[i] = c;
        tsum += c;
    }
    buf[t] = tsum;
    __syncthreads();
    for (int off = 1; off < 1024; off <<= 1) {
        uint32_t v = (t >= off) ? buf[t - off] : 0u;
        __syncthreads();
        buf[t] += v;
        __syncthreads();
    }
    uint32_t run = buf[t] - tsum;   // exclusive prefix of this thread's chunk
#pragma unroll
    for (int i = 0; i < CH; i++) {
        int idx = base + i;
        if (idx < N_TYPE) {
            offsets[idx] = run;
            count[idx]   = run;      // reuse count[] as the fill cursor
            run += local[i];
        } else if (idx == N_TYPE) {
            offsets[idx] = run;      // == NEDGE
        }
    }
}

// Bin source ids by destination (we never need the edge id itself)
__global__ __launch_bounds__(256) void fill_k(const int* __restrict__ src,
                                              const int* __restrict__ dst,
                                              uint32_t* __restrict__ cursor,
                                              uint32_t* __restrict__ edge_src) {
    int e = blockIdx.x * 256 + threadIdx.x;
    if (e >= NEDGE) return;
    uint32_t pos = atomicAdd(&cursor[dst[e]], 1u);
    edge_src[pos] = (uint32_t)src[e];
}

// One wave per destination node: segment max -> exp-weighted feature sum -> normalize.
// Scores recomputed from s_src/s_dst and cached in LDS (fallback recompute if deg>MAXDEG).
__global__ __launch_bounds__(256) void agg_k(const void* __restrict__ h_sent,
                                             const void* __restrict__ h_type,
                                             const float* __restrict__ s_src,
                                             const float* __restrict__ s_dst,
                                             const uint32_t* __restrict__ offsets,
                                             const uint32_t* __restrict__ edge_src,
                                             const uint32_t* __restrict__ flag,
                                             void* __restrict__ out) {
    __shared__ float sc[4 * MAXDEG];
    int j     = (blockIdx.x * 256 + threadIdx.x) >> 6;
    int wslot = threadIdx.x >> 6;
    int lane  = threadIdx.x & 63;
    bool valid = j < N_TYPE;
    bool isbf  = flag[0] != 0u;
    uint32_t beg = 0, deg = 0;
    float sdj = 0.0f;
    if (valid) {
        beg = offsets[j];
        deg = offsets[j + 1] - beg;
        sdj = s_dst[j];
    }
    float* mysc = &sc[wslot * MAXDEG];
    bool fits = (deg <= MAXDEG);
    // pass 1: scores (lanes stride over edges), cache in LDS, wave max
    float m = -INFINITY;
    for (uint32_t k = lane; k < deg; k += 64) {
        float v = s_src[edge_src[beg + k]] + sdj;
        v = v > 0.0f ? v : 0.01f * v;
        if (fits) mysc[k] = v;
        m = fmaxf(m, v);
    }
#pragma unroll
    for (int off = 32; off; off >>= 1) m = fmaxf(m, __shfl_xor(m, off, 64));
    __syncthreads();   // make LDS score cache visible (single barrier, all threads reach it)
    if (!valid) return;
    if (deg == 0) {    // isolated node keeps its input feature
        if (isbf) ((uint32_t*)out)[(size_t)j * 64 + lane] =
                      ((const uint32_t*)h_type)[(size_t)j * 64 + lane];
        else      ((float2*)out)[(size_t)j * 64 + lane] =
                      ((const float2*)h_type)[(size_t)j * 64 + lane];
        return;
    }
    // pass 2: whole wave walks edges; each lane owns 2 feature dims
    float denom = 0.0f, a0 = 0.0f, a1 = 0.0f;
    if (isbf) {
        for (uint32_t k = 0; k < deg; ++k) {
            float v;
            if (fits) v = mysc[k];
            else { v = s_src[edge_src[beg + k]] + sdj; v = v > 0.0f ? v : 0.01f * v; }
            float w = __expf(v - m);
            uint32_t s = edge_src[beg + k];
            uint32_t hv = ((const uint32_t*)h_sent)[(size_t)s * 64 + lane];
            a0 += w * bf2f(hv & 0xffffu);
            a1 += w * bf2f(hv >> 16);
            denom += w;
        }
    } else {
        for (uint32_t k = 0; k < deg; ++k) {
            float v;
            if (fits) v = mysc[k];
            else { v = s_src[edge_src[beg + k]] + sdj; v = v > 0.0f ? v : 0.01f * v; }
            float w = __expf(v - m);
            uint32_t s = edge_src[beg + k];
            float2 hv = ((const float2*)h_sent)[(size_t)s * 64 + lane];
            a0 += w * hv.x;
            a1 += w * hv.y;
            denom += w;
        }
    }
    float inv = 1.0f / denom;
    if (isbf) ((uint32_t*)out)[(size_t)j * 64 + lane] = f2bf(a0 * inv) | (f2bf(a1 * inv) << 16);
    else      ((float2*)out)[(size_t)j * 64 + lane]   = make_float2(a0 * inv, a1 * inv);
}

static inline size_t align_up(size_t x) { return (x + 255) & ~(size_t)255; }

extern "C" void kernel_launch(void* const* d_in, const int* in_sizes, int n_in,
                              void* d_out, int out_size, void* d_ws, size_t ws_size,
                              hipStream_t stream) {
    const void* h_sent = d_in[0];
    const void* h_type = d_in[1];
    const void* attn_w = d_in[2];
    const int* src_idx = (const int*)d_in[3];
    const int* dst_idx = (const int*)d_in[4];

    char* w = (char*)d_ws;
    uint32_t* flag      = (uint32_t*)w; w += 256;
    float*    s_src     = (float*)w;    w += align_up((size_t)N_SENT * 4);
    float*    s_dst     = (float*)w;    w += align_up((size_t)N_TYPE * 4);
    uint32_t* count     = (uint32_t*)w; w += align_up((size_t)N_TYPE * 4);
    uint32_t* offsets   = (uint32_t*)w; w += align_up((size_t)(N_TYPE + 1) * 4);
    uint32_t* edge_src  = (uint32_t*)w; w += align_up((size_t)NEDGE * 4);
    // total ~3.08 MB

    detect_k<<<1, 64, 0, stream>>>((const uint32_t*)h_sent, flag);
    zero_u32_k<<<(N_TYPE + 255) / 256, 256, 0, stream>>>(count, N_TYPE);
    int nwaves = N_SENT + N_TYPE;
    scores_k<<<(nwaves + 3) / 4, 256, 0, stream>>>(h_sent, h_type, attn_w, flag, s_src, s_dst);
    count_k<<<(NEDGE + 255) / 256, 256, 0, stream>>>(dst_idx, count);
    scan_k<<<1, 1024, 0, stream>>>(count, offsets);
    fill_k<<<(NEDGE + 255) / 256, 256, 0, stream>>>(src_idx, dst_idx, count, edge_src);
    agg_k<<<(N_TYPE + 3) / 4, 256, 0, stream>>>(h_sent, h_type, s_src, s_dst,
                                                offsets, edge_src, flag, d_out);
}

// Round 3
// 241.067 us; speedup vs baseline: 1.1170x; 1.1170x over previous
//
#include <hip/hip_runtime.h>
#include <stdint.h>
#include <stddef.h>

#define N_SENT 100000
#define N_TYPE 10000
#define NEDGE  640000
#define MAXDEG 256   // LDS cache per wave; Poisson(64): P(deg>256) ~ 0. Fallback path exists.

__device__ __forceinline__ float bf2f(uint32_t lo16) {
    return __builtin_bit_cast(float, lo16 << 16);
}
__device__ __forceinline__ uint32_t f2bf(float f) {
    uint32_t u = __builtin_bit_cast(uint32_t, f);
    return (u + 0x7fffu + ((u >> 16) & 1u)) >> 16;
}

// ---- fused: dtype detect (block 0) + zero count[] (all blocks) ----
// bf16 N(0,1) data: low halfword exponent in [100,140]. f32 low halfwords: uniform bits.
__global__ __launch_bounds__(256) void detect_zero_k(const uint32_t* __restrict__ h,
                                                     uint32_t* __restrict__ flag,
                                                     uint32_t* __restrict__ count) {
    int i = blockIdx.x * 256 + threadIdx.x;
    if (i < N_TYPE) count[i] = 0u;
    if (blockIdx.x == 0 && threadIdx.x < 64) {
        int lane = threadIdx.x;
        uint32_t u = h[lane];
        uint32_t e_lo = (u >> 7) & 0xffu;
        int ok = (e_lo >= 100u && e_lo <= 140u) ? 1 : 0;
        unsigned long long m = __ballot(ok);
        if (lane == 0) flag[0] = (__popcll(m) >= 48) ? 1u : 0u;
    }
}

#define SCORE_BLOCKS ((N_SENT + N_TYPE + 3) / 4)   // 27500, 4 waves/block, 1 row/wave
#define COUNT_BLOCKS ((NEDGE + 255) / 256)         // 2500

// ---- fused: per-row scores (blocks [0,SCORE_BLOCKS)) + per-dst degree count ----
__global__ __launch_bounds__(256) void scores_count_k(const void* __restrict__ h_sent,
                                                      const void* __restrict__ h_type,
                                                      const void* __restrict__ attn_w,
                                                      const int* __restrict__ dst,
                                                      const uint32_t* __restrict__ flag,
                                                      float* __restrict__ s_src,
                                                      float* __restrict__ s_dst,
                                                      uint32_t* __restrict__ count) {
    int b = blockIdx.x;
    if (b < SCORE_BLOCKS) {
        int wid  = (b * 256 + (int)threadIdx.x) >> 6;
        int lane = threadIdx.x & 63;
        if (wid >= N_SENT + N_TYPE) return;
        bool isSrc = wid < N_SENT;
        int row  = isSrc ? wid : wid - N_SENT;
        int widx = isSrc ? lane : 64 + lane;
        const void* h = isSrc ? h_sent : h_type;
        float sum;
        if (flag[0]) {
            uint32_t hv = ((const uint32_t*)h)[(size_t)row * 64 + lane];
            uint32_t wv = ((const uint32_t*)attn_w)[widx];
            sum = bf2f(hv & 0xffffu) * bf2f(wv & 0xffffu)
                + bf2f(hv >> 16)     * bf2f(wv >> 16);
        } else {
            float2 hv = ((const float2*)h)[(size_t)row * 64 + lane];
            float2 wv = ((const float2*)attn_w)[widx];
            sum = hv.x * wv.x + hv.y * wv.y;
        }
#pragma unroll
        for (int off = 32; off; off >>= 1) sum += __shfl_xor(sum, off, 64);
        if (lane == 0) {
            if (isSrc) s_src[row] = sum;
            else       s_dst[row] = sum;
        }
    } else {
        int e = (b - SCORE_BLOCKS) * 256 + threadIdx.x;
        if (e < NEDGE) atomicAdd(&count[dst[e]], 1u);
    }
}

// ---- single-block exclusive scan via wave shuffles (2 barriers) ----
__global__ __launch_bounds__(1024) void scan_k(uint32_t* __restrict__ count,
                                               uint32_t* __restrict__ offsets) {
    const int CH = 10;   // 1024*10 >= N_TYPE
    int t = threadIdx.x, lane = t & 63, wv = t >> 6;   // 16 waves
    int base = t * CH;
    uint32_t local[CH];
    uint32_t tsum = 0;
#pragma unroll
    for (int i = 0; i < CH; i++) {
        int idx = base + i;
        uint32_t c = (idx < N_TYPE) ? count[idx] : 0u;
        local[i] = c;
        tsum += c;
    }
    uint32_t orig = tsum;
    // inclusive shuffle-scan within wave
#pragma unroll
    for (int off = 1; off < 64; off <<= 1) {
        uint32_t v = __shfl_up(tsum, off, 64);
        if (lane >= off) tsum += v;
    }
    __shared__ uint32_t wsum[16];
    if (lane == 63) wsum[wv] = tsum;
    __syncthreads();
    if (wv == 0 && lane < 16) {
        uint32_t u = wsum[lane], o = u;
#pragma unroll
        for (int off = 1; off < 16; off <<= 1) {
            uint32_t v = __shfl_up(u, off, 64);
            if (lane >= off) u += v;
        }
        wsum[lane] = u - o;   // exclusive wave prefix
    }
    __syncthreads();
    uint32_t run = wsum[wv] + tsum - orig;   // exclusive thread prefix
#pragma unroll
    for (int i = 0; i < CH; i++) {
        int idx = base + i;
        if (idx < N_TYPE) {
            offsets[idx] = run;
            count[idx]   = run;   // reuse count[] as fill cursor
            run += local[i];
        } else if (idx == N_TYPE) {
            offsets[idx] = run;   // == NEDGE
        }
    }
}

// ---- bin source ids by destination ----
__global__ __launch_bounds__(256) void fill_k(const int* __restrict__ src,
                                              const int* __restrict__ dst,
                                              uint32_t* __restrict__ cursor,
                                              uint32_t* __restrict__ edge_src) {
    int e = blockIdx.x * 256 + threadIdx.x;
    if (e >= NEDGE) return;
    uint32_t pos = atomicAdd(&cursor[dst[e]], 1u);
    edge_src[pos] = (uint32_t)src[e];
}

// ---- one wave per destination: max -> exp-weighted gather-sum (x8 unrolled) -> normalize
__global__ __launch_bounds__(256) void agg_k(const void* __restrict__ h_sent,
                                             const void* __restrict__ h_type,
                                             const float* __restrict__ s_src,
                                             const float* __restrict__ s_dst,
                                             const uint32_t* __restrict__ offsets,
                                             const uint32_t* __restrict__ edge_src,
                                             const uint32_t* __restrict__ flag,
                                             void* __restrict__ out) {
    __shared__ float    sc[4][MAXDEG];
    __shared__ uint32_t ss[4][MAXDEG];
    int j     = (blockIdx.x * 256 + threadIdx.x) >> 6;
    int wslot = threadIdx.x >> 6;
    int lane  = threadIdx.x & 63;
    bool valid = j < N_TYPE;
    bool isbf  = flag[0] != 0u;
    uint32_t beg = 0, deg = 0;
    float sdj = 0.0f;
    if (valid) {
        beg = offsets[j];
        deg = offsets[j + 1] - beg;
        sdj = s_dst[j];
    }
    float*    mysc = sc[wslot];
    uint32_t* myss = ss[wslot];
    bool fits = (deg <= MAXDEG);
    // pass 1: scores, cache (score, src) in LDS, wave max
    float m = -INFINITY;
    for (uint32_t k = lane; k < deg; k += 64) {
        uint32_t s = edge_src[beg + k];
        float v = s_src[s] + sdj;
        v = v > 0.0f ? v : 0.01f * v;
        if (fits) { mysc[k] = v; myss[k] = s; }
        m = fmaxf(m, v);
    }
#pragma unroll
    for (int off = 32; off; off >>= 1) m = fmaxf(m, __shfl_xor(m, off, 64));
    __syncthreads();   // LDS visibility (uniform: every thread reaches this)
    if (!valid) return;
    if (deg == 0) {    // isolated node keeps its input feature
        if (isbf) ((uint32_t*)out)[(size_t)j * 64 + lane] =
                      ((const uint32_t*)h_type)[(size_t)j * 64 + lane];
        else      ((float2*)out)[(size_t)j * 64 + lane] =
                      ((const float2*)h_type)[(size_t)j * 64 + lane];
        return;
    }
    float denom = 0.0f, a0 = 0.0f, a1 = 0.0f;
    if (isbf) {
        const uint32_t* hp = (const uint32_t*)h_sent;
        uint32_t k = 0;
        if (fits) {
            for (; k + 8 <= deg; k += 8) {
                uint32_t sv[8]; float vv[8]; uint32_t gv[8];
#pragma unroll
                for (int i = 0; i < 8; i++) { sv[i] = myss[k + i]; vv[i] = mysc[k + i]; }
#pragma unroll
                for (int i = 0; i < 8; i++) gv[i] = hp[(size_t)sv[i] * 64 + lane];
#pragma unroll
                for (int i = 0; i < 8; i++) {
                    float w = __expf(vv[i] - m);
                    denom += w;
                    a0 += w * bf2f(gv[i] & 0xffffu);
                    a1 += w * bf2f(gv[i] >> 16);
                }
            }
            for (; k < deg; ++k) {
                float w = __expf(mysc[k] - m);
                uint32_t g = hp[(size_t)myss[k] * 64 + lane];
                denom += w;
                a0 += w * bf2f(g & 0xffffu);
                a1 += w * bf2f(g >> 16);
            }
        } else {
            for (k = 0; k < deg; ++k) {
                uint32_t s = edge_src[beg + k];
                float v = s_src[s] + sdj; v = v > 0.0f ? v : 0.01f * v;
                float w = __expf(v - m);
                uint32_t g = hp[(size_t)s * 64 + lane];
                denom += w;
                a0 += w * bf2f(g & 0xffffu);
                a1 += w * bf2f(g >> 16);
            }
        }
        float inv = 1.0f / denom;
        ((uint32_t*)out)[(size_t)j * 64 + lane] = f2bf(a0 * inv) | (f2bf(a1 * inv) << 16);
    } else {
        const float2* hp = (const float2*)h_sent;
        uint32_t k = 0;
        if (fits) {
            for (; k + 8 <= deg; k += 8) {
                uint32_t sv[8]; float vv[8]; float2 gv[8];
#pragma unroll
                for (int i = 0; i < 8; i++) { sv[i] = myss[k + i]; vv[i] = mysc[k + i]; }
#pragma unroll
                for (int i = 0; i < 8; i++) gv[i] = hp[(size_t)sv[i] * 64 + lane];
#pragma unroll
                for (int i = 0; i < 8; i++) {
                    float w = __expf(vv[i] - m);
                    denom += w;
                    a0 += w * gv[i].x;
                    a1 += w * gv[i].y;
                }
            }
            for (; k < deg; ++k) {
                float w = __expf(mysc[k] - m);
                float2 g = hp[(size_t)myss[k] * 64 + lane];
                denom += w;
                a0 += w * g.x;
                a1 += w * g.y;
            }
        } else {
            for (k = 0; k < deg; ++k) {
                uint32_t s = edge_src[beg + k];
                float v = s_src[s] + sdj; v = v > 0.0f ? v : 0.01f * v;
                float w = __expf(v - m);
                float2 g = hp[(size_t)s * 64 + lane];
                denom += w;
                a0 += w * g.x;
                a1 += w * g.y;
            }
        }
        float inv = 1.0f / denom;
        ((float2*)out)[(size_t)j * 64 + lane] = make_float2(a0 * inv, a1 * inv);
    }
}

static inline size_t align_up(size_t x) { return (x + 255) & ~(size_t)255; }

extern "C" void kernel_launch(void* const* d_in, const int* in_sizes, int n_in,
                              void* d_out, int out_size, void* d_ws, size_t ws_size,
                              hipStream_t stream) {
    const void* h_sent = d_in[0];
    const void* h_type = d_in[1];
    const void* attn_w = d_in[2];
    const int* src_idx = (const int*)d_in[3];
    const int* dst_idx = (const int*)d_in[4];

    char* w = (char*)d_ws;
    uint32_t* flag      = (uint32_t*)w; w += 256;
    float*    s_src     = (float*)w;    w += align_up((size_t)N_SENT * 4);
    float*    s_dst     = (float*)w;    w += align_up((size_t)N_TYPE * 4);
    uint32_t* count     = (uint32_t*)w; w += align_up((size_t)N_TYPE * 4);
    uint32_t* offsets   = (uint32_t*)w; w += align_up((size_t)(N_TYPE + 1) * 4);
    uint32_t* edge_src  = (uint32_t*)w; w += align_up((size_t)NEDGE * 4);
    // total ~3.08 MB

    detect_zero_k<<<(N_TYPE + 255) / 256, 256, 0, stream>>>(
        (const uint32_t*)h_sent, flag, count);
    scores_count_k<<<SCORE_BLOCKS + COUNT_BLOCKS, 256, 0, stream>>>(
        h_sent, h_type, attn_w, dst_idx, flag, s_src, s_dst, count);
    scan_k<<<1, 1024, 0, stream>>>(count, offsets);
    fill_k<<<(NEDGE + 255) / 256, 256, 0, stream>>>(src_idx, dst_idx, count, edge_src);
    agg_k<<<(N_TYPE + 3) / 4, 256, 0, stream>>>(h_sent, h_type, s_src, s_dst,
                                                offsets, edge_src, flag, d_out);
}

// Round 4
// 231.756 us; speedup vs baseline: 1.1619x; 1.0402x over previous
//
#include <hip/hip_runtime.h>
#include <stdint.h>
#include <stddef.h>

#define N_SENT 100000
#define N_TYPE 10000
#define NEDGE  640000
#define NROWS  (N_SENT + N_TYPE)
#define MAXDEG 256   // LDS cache per wave; Poisson(64): P(deg>256) ~ 0. Fallback path exists.

__device__ __forceinline__ float bf2f(uint32_t lo16) {
    return __builtin_bit_cast(float, lo16 << 16);
}
__device__ __forceinline__ uint32_t f2bf(float f) {
    uint32_t u = __builtin_bit_cast(uint32_t, f);
    return (u + 0x7fffu + ((u >> 16) & 1u)) >> 16;
}

// ---- fused: dtype detect (block 0) + zero count[] (all blocks) ----
// bf16 N(0,1) data: low halfword exponent in [100,140]. f32 low halfwords: uniform bits.
__global__ __launch_bounds__(256) void detect_zero_k(const uint32_t* __restrict__ h,
                                                     uint32_t* __restrict__ flag,
                                                     uint32_t* __restrict__ count) {
    int i = blockIdx.x * 256 + threadIdx.x;
    if (i < N_TYPE) count[i] = 0u;
    if (blockIdx.x == 0 && threadIdx.x < 64) {
        int lane = threadIdx.x;
        uint32_t u = h[lane];
        uint32_t e_lo = (u >> 7) & 0xffu;
        int ok = (e_lo >= 100u && e_lo <= 140u) ? 1 : 0;
        unsigned long long m = __ballot(ok);
        if (lane == 0) flag[0] = (__popcll(m) >= 48) ? 1u : 0u;
    }
}

// 8 rows per wave, 4 waves per block -> 32 rows per block
#define SCORE_BLOCKS ((NROWS + 31) / 32)     // 3438
#define COUNT_BLOCKS ((NEDGE + 255) / 256)   // 2500

// ---- fused: per-row scores (multi-row butterfly GEMV) + per-dst degree count ----
__global__ __launch_bounds__(256) void scores_count_k(const void* __restrict__ h_sent,
                                                      const void* __restrict__ h_type,
                                                      const void* __restrict__ attn_w,
                                                      const int* __restrict__ dst,
                                                      const uint32_t* __restrict__ flag,
                                                      float* __restrict__ s_src,
                                                      float* __restrict__ s_dst,
                                                      uint32_t* __restrict__ count) {
    int b = blockIdx.x;
    if (b < SCORE_BLOCKS) {
        int lane = threadIdx.x & 63;
        int r0   = (b * 4 + (int)(threadIdx.x >> 6)) * 8;   // first of 8 rows for this wave
        float v[8];
        if (flag[0]) {   // ---- bf16: one u32 (2 elems) per lane per row ----
            uint32_t wv_s = ((const uint32_t*)attn_w)[lane];
            uint32_t wv_t = ((const uint32_t*)attn_w)[64 + lane];
            float ws0 = bf2f(wv_s & 0xffffu), ws1 = bf2f(wv_s >> 16);
            float wt0 = bf2f(wv_t & 0xffffu), wt1 = bf2f(wv_t >> 16);
#pragma unroll
            for (int i = 0; i < 8; i++) {
                int g = r0 + i;
                if (g >= NROWS) { v[i] = 0.0f; continue; }
                bool isSrc = g < N_SENT;
                const uint32_t* hp = isSrc
                    ? (const uint32_t*)h_sent + (size_t)g * 64
                    : (const uint32_t*)h_type + (size_t)(g - N_SENT) * 64;
                uint32_t hv = hp[lane];
                v[i] = isSrc ? (bf2f(hv & 0xffffu) * ws0 + bf2f(hv >> 16) * ws1)
                             : (bf2f(hv & 0xffffu) * wt0 + bf2f(hv >> 16) * wt1);
            }
        } else {        // ---- f32: one float2 per lane per row ----
            float2 wv_s = ((const float2*)attn_w)[lane];
            float2 wv_t = ((const float2*)attn_w)[64 + lane];
#pragma unroll
            for (int i = 0; i < 8; i++) {
                int g = r0 + i;
                if (g >= NROWS) { v[i] = 0.0f; continue; }
                bool isSrc = g < N_SENT;
                const float2* hp = isSrc
                    ? (const float2*)h_sent + (size_t)g * 64
                    : (const float2*)h_type + (size_t)(g - N_SENT) * 64;
                float2 hv = hp[lane];
                v[i] = isSrc ? (hv.x * wv_s.x + hv.y * wv_s.y)
                             : (hv.x * wv_t.x + hv.y * wv_t.y);
            }
        }
        // multi-value butterfly: 3 merge stages fold 8 rows -> 1 value/lane (row = lane&7)
        int b0 = lane & 1, b1 = (lane >> 1) & 1, b2 = (lane >> 2) & 1;
        float w_[4];
#pragma unroll
        for (int i = 0; i < 4; i++) {
            float keep = b0 ? v[2 * i + 1] : v[2 * i];
            float send = b0 ? v[2 * i]     : v[2 * i + 1];
            w_[i] = keep + __shfl_xor(send, 1, 64);
        }
        float x_[2];
#pragma unroll
        for (int jj = 0; jj < 2; jj++) {
            float keep = b1 ? w_[2 * jj + 1] : w_[2 * jj];
            float send = b1 ? w_[2 * jj]     : w_[2 * jj + 1];
            x_[jj] = keep + __shfl_xor(send, 2, 64);
        }
        {
            float keep = b2 ? x_[1] : x_[0];
            float send = b2 ? x_[0] : x_[1];
            v[0] = keep + __shfl_xor(send, 4, 64);
        }
#pragma unroll
        for (int off = 8; off < 64; off <<= 1) v[0] += __shfl_xor(v[0], off, 64);
        // lanes 0..7 hold rows r0..r0+7
        if (lane < 8) {
            int g = r0 + lane;
            if (g < NROWS) {
                if (g < N_SENT) s_src[g] = v[0];
                else            s_dst[g - N_SENT] = v[0];
            }
        }
    } else {
        int e = (b - SCORE_BLOCKS) * 256 + threadIdx.x;
        if (e < NEDGE) atomicAdd(&count[dst[e]], 1u);
    }
}

// ---- single-block exclusive scan via wave shuffles (2 barriers) ----
__global__ __launch_bounds__(1024) void scan_k(uint32_t* __restrict__ count,
                                               uint32_t* __restrict__ offsets) {
    const int CH = 10;   // 1024*10 >= N_TYPE
    int t = threadIdx.x, lane = t & 63, wv = t >> 6;   // 16 waves
    int base = t * CH;
    uint32_t local[CH];
    uint32_t tsum = 0;
#pragma unroll
    for (int i = 0; i < CH; i++) {
        int idx = base + i;
        uint32_t c = (idx < N_TYPE) ? count[idx] : 0u;
        local[i] = c;
        tsum += c;
    }
    uint32_t orig = tsum;
#pragma unroll
    for (int off = 1; off < 64; off <<= 1) {
        uint32_t v = __shfl_up(tsum, off, 64);
        if (lane >= off) tsum += v;
    }
    __shared__ uint32_t wsum[16];
    if (lane == 63) wsum[wv] = tsum;
    __syncthreads();
    if (wv == 0 && lane < 16) {
        uint32_t u = wsum[lane], o = u;
#pragma unroll
        for (int off = 1; off < 16; off <<= 1) {
            uint32_t v = __shfl_up(u, off, 64);
            if (lane >= off) u += v;
        }
        wsum[lane] = u - o;   // exclusive wave prefix
    }
    __syncthreads();
    uint32_t run = wsum[wv] + tsum - orig;   // exclusive thread prefix
#pragma unroll
    for (int i = 0; i < CH; i++) {
        int idx = base + i;
        if (idx < N_TYPE) {
            offsets[idx] = run;
            count[idx]   = run;   // reuse count[] as fill cursor
            run += local[i];
        } else if (idx == N_TYPE) {
            offsets[idx] = run;   // == NEDGE
        }
    }
}

// ---- bin source ids by destination ----
__global__ __launch_bounds__(256) void fill_k(const int* __restrict__ src,
                                              const int* __restrict__ dst,
                                              uint32_t* __restrict__ cursor,
                                              uint32_t* __restrict__ edge_src) {
    int e = blockIdx.x * 256 + threadIdx.x;
    if (e >= NEDGE) return;
    uint32_t pos = atomicAdd(&cursor[dst[e]], 1u);
    edge_src[pos] = (uint32_t)src[e];
}

// ---- one wave per destination: max -> exp-weighted gather-sum (x8 unrolled) -> normalize
__global__ __launch_bounds__(256) void agg_k(const void* __restrict__ h_sent,
                                             const void* __restrict__ h_type,
                                             const float* __restrict__ s_src,
                                             const float* __restrict__ s_dst,
                                             const uint32_t* __restrict__ offsets,
                                             const uint32_t* __restrict__ edge_src,
                                             const uint32_t* __restrict__ flag,
                                             void* __restrict__ out) {
    __shared__ float    sc[4][MAXDEG];
    __shared__ uint32_t ss[4][MAXDEG];
    int j     = (blockIdx.x * 256 + threadIdx.x) >> 6;
    int wslot = threadIdx.x >> 6;
    int lane  = threadIdx.x & 63;
    bool valid = j < N_TYPE;
    bool isbf  = flag[0] != 0u;
    uint32_t beg = 0, deg = 0;
    float sdj = 0.0f;
    if (valid) {
        beg = offsets[j];
        deg = offsets[j + 1] - beg;
        sdj = s_dst[j];
    }
    float*    mysc = sc[wslot];
    uint32_t* myss = ss[wslot];
    bool fits = (deg <= MAXDEG);
    float m = -INFINITY;
    for (uint32_t k = lane; k < deg; k += 64) {
        uint32_t s = edge_src[beg + k];
        float v = s_src[s] + sdj;
        v = v > 0.0f ? v : 0.01f * v;
        if (fits) { mysc[k] = v; myss[k] = s; }
        m = fmaxf(m, v);
    }
#pragma unroll
    for (int off = 32; off; off >>= 1) m = fmaxf(m, __shfl_xor(m, off, 64));
    __syncthreads();   // LDS visibility (uniform: every thread reaches this)
    if (!valid) return;
    if (deg == 0) {    // isolated node keeps its input feature
        if (isbf) ((uint32_t*)out)[(size_t)j * 64 + lane] =
                      ((const uint32_t*)h_type)[(size_t)j * 64 + lane];
        else      ((float2*)out)[(size_t)j * 64 + lane] =
                      ((const float2*)h_type)[(size_t)j * 64 + lane];
        return;
    }
    float denom = 0.0f, a0 = 0.0f, a1 = 0.0f;
    if (isbf) {
        const uint32_t* hp = (const uint32_t*)h_sent;
        uint32_t k = 0;
        if (fits) {
            for (; k + 8 <= deg; k += 8) {
                uint32_t sv[8]; float vv[8]; uint32_t gv[8];
#pragma unroll
                for (int i = 0; i < 8; i++) { sv[i] = myss[k + i]; vv[i] = mysc[k + i]; }
#pragma unroll
                for (int i = 0; i < 8; i++) gv[i] = hp[(size_t)sv[i] * 64 + lane];
#pragma unroll
                for (int i = 0; i < 8; i++) {
                    float w = __expf(vv[i] - m);
                    denom += w;
                    a0 += w * bf2f(gv[i] & 0xffffu);
                    a1 += w * bf2f(gv[i] >> 16);
                }
            }
            for (; k < deg; ++k) {
                float w = __expf(mysc[k] - m);
                uint32_t g = hp[(size_t)myss[k] * 64 + lane];
                denom += w;
                a0 += w * bf2f(g & 0xffffu);
                a1 += w * bf2f(g >> 16);
            }
        } else {
            for (k = 0; k < deg; ++k) {
                uint32_t s = edge_src[beg + k];
                float v = s_src[s] + sdj; v = v > 0.0f ? v : 0.01f * v;
                float w = __expf(v - m);
                uint32_t g = hp[(size_t)s * 64 + lane];
                denom += w;
                a0 += w * bf2f(g & 0xffffu);
                a1 += w * bf2f(g >> 16);
            }
        }
        float inv = 1.0f / denom;
        ((uint32_t*)out)[(size_t)j * 64 + lane] = f2bf(a0 * inv) | (f2bf(a1 * inv) << 16);
    } else {
        const float2* hp = (const float2*)h_sent;
        uint32_t k = 0;
        if (fits) {
            for (; k + 8 <= deg; k += 8) {
                uint32_t sv[8]; float vv[8]; float2 gv[8];
#pragma unroll
                for (int i = 0; i < 8; i++) { sv[i] = myss[k + i]; vv[i] = mysc[k + i]; }
#pragma unroll
                for (int i = 0; i < 8; i++) gv[i] = hp[(size_t)sv[i] * 64 + lane];
#pragma unroll
                for (int i = 0; i < 8; i++) {
                    float w = __expf(vv[i] - m);
                    denom += w;
                    a0 += w * gv[i].x;
                    a1 += w * gv[i].y;
                }
            }
            for (; k < deg; ++k) {
                float w = __expf(mysc[k] - m);
                float2 g = hp[(size_t)myss[k] * 64 + lane];
                denom += w;
                a0 += w * g.x;
                a1 += w * g.y;
            }
        } else {
            for (k = 0; k < deg; ++k) {
                uint32_t s = edge_src[beg + k];
                float v = s_src[s] + sdj; v = v > 0.0f ? v : 0.01f * v;
                float w = __expf(v - m);
                float2 g = hp[(size_t)s * 64 + lane];
                denom += w;
                a0 += w * g.x;
                a1 += w * g.y;
            }
        }
        float inv = 1.0f / denom;
        ((float2*)out)[(size_t)j * 64 + lane] = make_float2(a0 * inv, a1 * inv);
    }
}

static inline size_t align_up(size_t x) { return (x + 255) & ~(size_t)255; }

extern "C" void kernel_launch(void* const* d_in, const int* in_sizes, int n_in,
                              void* d_out, int out_size, void* d_ws, size_t ws_size,
                              hipStream_t stream) {
    const void* h_sent = d_in[0];
    const void* h_type = d_in[1];
    const void* attn_w = d_in[2];
    const int* src_idx = (const int*)d_in[3];
    const int* dst_idx = (const int*)d_in[4];

    char* w = (char*)d_ws;
    uint32_t* flag      = (uint32_t*)w; w += 256;
    float*    s_src     = (float*)w;    w += align_up((size_t)N_SENT * 4);
    float*    s_dst     = (float*)w;    w += align_up((size_t)N_TYPE * 4);
    uint32_t* count     = (uint32_t*)w; w += align_up((size_t)N_TYPE * 4);
    uint32_t* offsets   = (uint32_t*)w; w += align_up((size_t)(N_TYPE + 1) * 4);
    uint32_t* edge_src  = (uint32_t*)w; w += align_up((size_t)NEDGE * 4);
    // total ~3.08 MB

    detect_zero_k<<<(N_TYPE + 255) / 256, 256, 0, stream>>>(
        (const uint32_t*)h_sent, flag, count);
    scores_count_k<<<SCORE_BLOCKS + COUNT_BLOCKS, 256, 0, stream>>>(
        h_sent, h_type, attn_w, dst_idx, flag, s_src, s_dst, count);
    scan_k<<<1, 1024, 0, stream>>>(count, offsets);
    fill_k<<<(NEDGE + 255) / 256, 256, 0, stream>>>(src_idx, dst_idx, count, edge_src);
    agg_k<<<(N_TYPE + 3) / 4, 256, 0, stream>>>(h_sent, h_type, s_src, s_dst,
                                                offsets, edge_src, flag, d_out);
}

// Round 5
// 230.018 us; speedup vs baseline: 1.1707x; 1.0076x over previous
//
#include <hip/hip_runtime.h>
#include <stdint.h>
#include <stddef.h>

#define N_SENT 100000
#define N_TYPE 10000
#define NEDGE  640000
#define NROWS  (N_SENT + N_TYPE)
#define MAXDEG 256    // LDS cache per wave in agg_k; Poisson(64): P(deg>256) ~ 0. Fallback exists.
#define HB     64     // histogram blocks; 64 * 10000 == NEDGE exactly
#define HCHUNK (NEDGE / HB)

__device__ __forceinline__ float bf2f(uint32_t lo16) {
    return __builtin_bit_cast(float, lo16 << 16);
}
__device__ __forceinline__ uint32_t f2bf(float f) {
    uint32_t u = __builtin_bit_cast(uint32_t, f);
    return (u + 0x7fffu + ((u >> 16) & 1u)) >> 16;
}

// ---- fused: dtype detect (block 0) + zero count[] ----
__global__ __launch_bounds__(256) void detect_zero_k(const uint32_t* __restrict__ h,
                                                     uint32_t* __restrict__ flag,
                                                     uint32_t* __restrict__ count) {
    int i = blockIdx.x * 256 + threadIdx.x;
    if (i < N_TYPE) count[i] = 0u;
    if (blockIdx.x == 0 && threadIdx.x < 64) {
        int lane = threadIdx.x;
        uint32_t u = h[lane];
        uint32_t e_lo = (u >> 7) & 0xffu;
        int ok = (e_lo >= 100u && e_lo <= 140u) ? 1 : 0;
        unsigned long long m = __ballot(ok);
        if (lane == 0) flag[0] = (__popcll(m) >= 48) ? 1u : 0u;
    }
}

// 8 rows per wave, 4 waves per block -> 32 rows per block
#define SCORE_BLOCKS ((NROWS + 31) / 32)     // 3438

// ---- fused: per-row scores (multi-row butterfly GEMV) + LDS-privatized degree count ----
__global__ __launch_bounds__(256) void scores_count_k(const void* __restrict__ h_sent,
                                                      const void* __restrict__ h_type,
                                                      const void* __restrict__ attn_w,
                                                      const int* __restrict__ dst,
                                                      const uint32_t* __restrict__ flag,
                                                      float* __restrict__ s_src,
                                                      float* __restrict__ s_dst,
                                                      uint32_t* __restrict__ count) {
    __shared__ uint32_t hist[N_TYPE];   // used only by count blocks (40 KB)
    int b = blockIdx.x;
    if (b < SCORE_BLOCKS) {
        int lane = threadIdx.x & 63;
        int r0   = (b * 4 + (int)(threadIdx.x >> 6)) * 8;   // first of 8 rows for this wave
        float v[8];
        if (flag[0]) {   // ---- bf16 ----
            uint32_t wv_s = ((const uint32_t*)attn_w)[lane];
            uint32_t wv_t = ((const uint32_t*)attn_w)[64 + lane];
            float ws0 = bf2f(wv_s & 0xffffu), ws1 = bf2f(wv_s >> 16);
            float wt0 = bf2f(wv_t & 0xffffu), wt1 = bf2f(wv_t >> 16);
#pragma unroll
            for (int i = 0; i < 8; i++) {
                int g = r0 + i;
                if (g >= NROWS) { v[i] = 0.0f; continue; }
                bool isSrc = g < N_SENT;
                const uint32_t* hp = isSrc
                    ? (const uint32_t*)h_sent + (size_t)g * 64
                    : (const uint32_t*)h_type + (size_t)(g - N_SENT) * 64;
                uint32_t hv = hp[lane];
                v[i] = isSrc ? (bf2f(hv & 0xffffu) * ws0 + bf2f(hv >> 16) * ws1)
                             : (bf2f(hv & 0xffffu) * wt0 + bf2f(hv >> 16) * wt1);
            }
        } else {        // ---- f32 ----
            float2 wv_s = ((const float2*)attn_w)[lane];
            float2 wv_t = ((const float2*)attn_w)[64 + lane];
#pragma unroll
            for (int i = 0; i < 8; i++) {
                int g = r0 + i;
                if (g >= NROWS) { v[i] = 0.0f; continue; }
                bool isSrc = g < N_SENT;
                const float2* hp = isSrc
                    ? (const float2*)h_sent + (size_t)g * 64
                    : (const float2*)h_type + (size_t)(g - N_SENT) * 64;
                float2 hv = hp[lane];
                v[i] = isSrc ? (hv.x * wv_s.x + hv.y * wv_s.y)
                             : (hv.x * wv_t.x + hv.y * wv_t.y);
            }
        }
        // fold 8 rows -> 1 value/lane (row = lane&7), then butterfly
        int b0 = lane & 1, b1 = (lane >> 1) & 1, b2 = (lane >> 2) & 1;
        float w_[4];
#pragma unroll
        for (int i = 0; i < 4; i++) {
            float keep = b0 ? v[2 * i + 1] : v[2 * i];
            float send = b0 ? v[2 * i]     : v[2 * i + 1];
            w_[i] = keep + __shfl_xor(send, 1, 64);
        }
        float x_[2];
#pragma unroll
        for (int jj = 0; jj < 2; jj++) {
            float keep = b1 ? w_[2 * jj + 1] : w_[2 * jj];
            float send = b1 ? w_[2 * jj]     : w_[2 * jj + 1];
            x_[jj] = keep + __shfl_xor(send, 2, 64);
        }
        {
            float keep = b2 ? x_[1] : x_[0];
            float send = b2 ? x_[0] : x_[1];
            v[0] = keep + __shfl_xor(send, 4, 64);
        }
#pragma unroll
        for (int off = 8; off < 64; off <<= 1) v[0] += __shfl_xor(v[0], off, 64);
        if (lane < 8) {
            int g = r0 + lane;
            if (g < NROWS) {
                if (g < N_SENT) s_src[g] = v[0];
                else            s_dst[g - N_SENT] = v[0];
            }
        }
    } else {
        // ---- count blocks: LDS histogram over a 10k-edge chunk, coalesced flush ----
        int cb = b - SCORE_BLOCKS;           // [0, HB)
        int t  = threadIdx.x;
        for (int i = t; i < N_TYPE; i += 256) hist[i] = 0u;
        __syncthreads();
        int e0 = cb * HCHUNK;
        for (int i = t; i < HCHUNK; i += 256)
            atomicAdd(&hist[dst[e0 + i]], 1u);
        __syncthreads();
        for (int i = t; i < N_TYPE; i += 256) {
            uint32_t c = hist[i];
            if (c) atomicAdd(&count[i], c);
        }
    }
}

// ---- single-block exclusive scan via wave shuffles (2 barriers) ----
__global__ __launch_bounds__(1024) void scan_k(uint32_t* __restrict__ count,
                                               uint32_t* __restrict__ offsets) {
    const int CH = 10;   // 1024*10 >= N_TYPE
    int t = threadIdx.x, lane = t & 63, wv = t >> 6;   // 16 waves
    int base = t * CH;
    uint32_t local[CH];
    uint32_t tsum = 0;
#pragma unroll
    for (int i = 0; i < CH; i++) {
        int idx = base + i;
        uint32_t c = (idx < N_TYPE) ? count[idx] : 0u;
        local[i] = c;
        tsum += c;
    }
    uint32_t orig = tsum;
#pragma unroll
    for (int off = 1; off < 64; off <<= 1) {
        uint32_t v = __shfl_up(tsum, off, 64);
        if (lane >= off) tsum += v;
    }
    __shared__ uint32_t wsum[16];
    if (lane == 63) wsum[wv] = tsum;
    __syncthreads();
    if (wv == 0 && lane < 16) {
        uint32_t u = wsum[lane], o = u;
#pragma unroll
        for (int off = 1; off < 16; off <<= 1) {
            uint32_t v = __shfl_up(u, off, 64);
            if (lane >= off) u += v;
        }
        wsum[lane] = u - o;   // exclusive wave prefix
    }
    __syncthreads();
    uint32_t run = wsum[wv] + tsum - orig;   // exclusive thread prefix
#pragma unroll
    for (int i = 0; i < CH; i++) {
        int idx = base + i;
        if (idx < N_TYPE) {
            offsets[idx] = run;
            count[idx]   = run;   // reuse count[] as fill cursor
            run += local[i];
        } else if (idx == N_TYPE) {
            offsets[idx] = run;   // == NEDGE
        }
    }
}

// ---- fill: LDS histogram -> block-range reserve (coalesced global atomics) -> LDS-cursor scatter
__global__ __launch_bounds__(256) void fill_k(const int* __restrict__ src,
                                              const int* __restrict__ dst,
                                              uint32_t* __restrict__ cursor,
                                              uint32_t* __restrict__ edge_src) {
    __shared__ uint32_t hist[N_TYPE];   // 40 KB: count, then becomes per-block cursor
    int cb = blockIdx.x;                // [0, HB)
    int t  = threadIdx.x;
    for (int i = t; i < N_TYPE; i += 256) hist[i] = 0u;
    __syncthreads();
    int e0 = cb * HCHUNK;
    for (int i = t; i < HCHUNK; i += 256)
        atomicAdd(&hist[dst[e0 + i]], 1u);
    __syncthreads();
    for (int i = t; i < N_TYPE; i += 256) {
        uint32_t c = hist[i];
        hist[i] = c ? atomicAdd(&cursor[i], c) : 0u;   // reserve contiguous range
    }
    __syncthreads();
    for (int i = t; i < HCHUNK; i += 256) {
        int e = e0 + i;
        uint32_t pos = atomicAdd(&hist[dst[e]], 1u);   // LDS cursor
        edge_src[pos] = (uint32_t)src[e];
    }
}

// ---- one wave per destination: max -> exp-weighted gather-sum (x8 unrolled) -> normalize
__global__ __launch_bounds__(256) void agg_k(const void* __restrict__ h_sent,
                                             const void* __restrict__ h_type,
                                             const float* __restrict__ s_src,
                                             const float* __restrict__ s_dst,
                                             const uint32_t* __restrict__ offsets,
                                             const uint32_t* __restrict__ edge_src,
                                             const uint32_t* __restrict__ flag,
                                             void* __restrict__ out) {
    __shared__ float    sc[4][MAXDEG];
    __shared__ uint32_t ss[4][MAXDEG];
    int j     = (blockIdx.x * 256 + threadIdx.x) >> 6;
    int wslot = threadIdx.x >> 6;
    int lane  = threadIdx.x & 63;
    bool valid = j < N_TYPE;
    bool isbf  = flag[0] != 0u;
    uint32_t beg = 0, deg = 0;
    float sdj = 0.0f;
    if (valid) {
        beg = offsets[j];
        deg = offsets[j + 1] - beg;
        sdj = s_dst[j];
    }
    float*    mysc = sc[wslot];
    uint32_t* myss = ss[wslot];
    bool fits = (deg <= MAXDEG);
    float m = -INFINITY;
    for (uint32_t k = lane; k < deg; k += 64) {
        uint32_t s = edge_src[beg + k];
        float v = s_src[s] + sdj;
        v = v > 0.0f ? v : 0.01f * v;
        if (fits) { mysc[k] = v; myss[k] = s; }
        m = fmaxf(m, v);
    }
#pragma unroll
    for (int off = 32; off; off >>= 1) m = fmaxf(m, __shfl_xor(m, off, 64));
    __syncthreads();   // LDS visibility (uniform: every thread reaches this)
    if (!valid) return;
    if (deg == 0) {    // isolated node keeps its input feature
        if (isbf) ((uint32_t*)out)[(size_t)j * 64 + lane] =
                      ((const uint32_t*)h_type)[(size_t)j * 64 + lane];
        else      ((float2*)out)[(size_t)j * 64 + lane] =
                      ((const float2*)h_type)[(size_t)j * 64 + lane];
        return;
    }
    float denom = 0.0f, a0 = 0.0f, a1 = 0.0f;
    if (isbf) {
        const uint32_t* hp = (const uint32_t*)h_sent;
        uint32_t k = 0;
        if (fits) {
            for (; k + 8 <= deg; k += 8) {
                uint32_t sv[8]; float vv[8]; uint32_t gv[8];
#pragma unroll
                for (int i = 0; i < 8; i++) { sv[i] = myss[k + i]; vv[i] = mysc[k + i]; }
#pragma unroll
                for (int i = 0; i < 8; i++) gv[i] = hp[(size_t)sv[i] * 64 + lane];
#pragma unroll
                for (int i = 0; i < 8; i++) {
                    float w = __expf(vv[i] - m);
                    denom += w;
                    a0 += w * bf2f(gv[i] & 0xffffu);
                    a1 += w * bf2f(gv[i] >> 16);
                }
            }
            for (; k < deg; ++k) {
                float w = __expf(mysc[k] - m);
                uint32_t g = hp[(size_t)myss[k] * 64 + lane];
                denom += w;
                a0 += w * bf2f(g & 0xffffu);
                a1 += w * bf2f(g >> 16);
            }
        } else {
            for (k = 0; k < deg; ++k) {
                uint32_t s = edge_src[beg + k];
                float v = s_src[s] + sdj; v = v > 0.0f ? v : 0.01f * v;
                float w = __expf(v - m);
                uint32_t g = hp[(size_t)s * 64 + lane];
                denom += w;
                a0 += w * bf2f(g & 0xffffu);
                a1 += w * bf2f(g >> 16);
            }
        }
        float inv = 1.0f / denom;
        ((uint32_t*)out)[(size_t)j * 64 + lane] = f2bf(a0 * inv) | (f2bf(a1 * inv) << 16);
    } else {
        const float2* hp = (const float2*)h_sent;
        uint32_t k = 0;
        if (fits) {
            for (; k + 8 <= deg; k += 8) {
                uint32_t sv[8]; float vv[8]; float2 gv[8];
#pragma unroll
                for (int i = 0; i < 8; i++) { sv[i] = myss[k + i]; vv[i] = mysc[k + i]; }
#pragma unroll
                for (int i = 0; i < 8; i++) gv[i] = hp[(size_t)sv[i] * 64 + lane];
#pragma unroll
                for (int i = 0; i < 8; i++) {
                    float w = __expf(vv[i] - m);
                    denom += w;
                    a0 += w * gv[i].x;
                    a1 += w * gv[i].y;
                }
            }
            for (; k < deg; ++k) {
                float w = __expf(mysc[k] - m);
                float2 g = hp[(size_t)myss[k] * 64 + lane];
                denom += w;
                a0 += w * g.x;
                a1 += w * g.y;
            }
        } else {
            for (k = 0; k < deg; ++k) {
                uint32_t s = edge_src[beg + k];
                float v = s_src[s] + sdj; v = v > 0.0f ? v : 0.01f * v;
                float w = __expf(v - m);
                float2 g = hp[(size_t)s * 64 + lane];
                denom += w;
                a0 += w * g.x;
                a1 += w * g.y;
            }
        }
        float inv = 1.0f / denom;
        ((float2*)out)[(size_t)j * 64 + lane] = make_float2(a0 * inv, a1 * inv);
    }
}

static inline size_t align_up(size_t x) { return (x + 255) & ~(size_t)255; }

extern "C" void kernel_launch(void* const* d_in, const int* in_sizes, int n_in,
                              void* d_out, int out_size, void* d_ws, size_t ws_size,
                              hipStream_t stream) {
    const void* h_sent = d_in[0];
    const void* h_type = d_in[1];
    const void* attn_w = d_in[2];
    const int* src_idx = (const int*)d_in[3];
    const int* dst_idx = (const int*)d_in[4];

    char* w = (char*)d_ws;
    uint32_t* flag      = (uint32_t*)w; w += 256;
    float*    s_src     = (float*)w;    w += align_up((size_t)N_SENT * 4);
    float*    s_dst     = (float*)w;    w += align_up((size_t)N_TYPE * 4);
    uint32_t* count     = (uint32_t*)w; w += align_up((size_t)N_TYPE * 4);
    uint32_t* offsets   = (uint32_t*)w; w += align_up((size_t)(N_TYPE + 1) * 4);
    uint32_t* edge_src  = (uint32_t*)w; w += align_up((size_t)NEDGE * 4);
    // total ~3.08 MB

    detect_zero_k<<<(N_TYPE + 255) / 256, 256, 0, stream>>>(
        (const uint32_t*)h_sent, flag, count);
    scores_count_k<<<SCORE_BLOCKS + HB, 256, 0, stream>>>(
        h_sent, h_type, attn_w, dst_idx, flag, s_src, s_dst, count);
    scan_k<<<1, 1024, 0, stream>>>(count, offsets);
    fill_k<<<HB, 256, 0, stream>>>(src_idx, dst_idx, count, edge_src);
    agg_k<<<(N_TYPE + 3) / 4, 256, 0, stream>>>(h_sent, h_type, s_src, s_dst,
                                                offsets, edge_src, flag, d_out);
}

// Round 6
// 198.311 us; speedup vs baseline: 1.3579x; 1.1599x over previous
//
#include <hip/hip_runtime.h>
#include <stdint.h>
#include <stddef.h>

#define N_SENT 100000
#define N_TYPE 10000
#define NEDGE  640000
#define NROWS  (N_SENT + N_TYPE)
#define MAXDEG 256    // LDS cache per wave in agg_k; Poisson(64): P(deg>256) ~ 0. Fallback exists.
#define HB     64     // histogram chunks; 64 * 10000 == NEDGE exactly
#define HCHUNK (NEDGE / HB)

__device__ __forceinline__ float bf2f(uint32_t lo16) {
    return __builtin_bit_cast(float, lo16 << 16);
}
__device__ __forceinline__ uint32_t f2bf(float f) {
    uint32_t u = __builtin_bit_cast(uint32_t, f);
    return (u + 0x7fffu + ((u >> 16) & 1u)) >> 16;
}

// Inline per-wave dtype probe: bf16 pairs have bf16-sane exponents in the low halfword;
// f32 low halfwords are mantissa bits (uniform). One broadcast load + ballot, wave-uniform.
__device__ __forceinline__ bool detect_bf16(const uint32_t* __restrict__ h) {
    uint32_t u = h[threadIdx.x & 63];
    uint32_t e_lo = (u >> 7) & 0xffu;
    int ok = (e_lo >= 100u && e_lo <= 140u) ? 1 : 0;
    unsigned long long m = __ballot(ok);
    return __popcll(m) >= 48;
}

// ---- scores: 16 rows per wave, 64 rows per block ----
#define SCORE_BLOCKS ((NROWS + 63) / 64)   // 1719

__global__ __launch_bounds__(256) void scores_k(const void* __restrict__ h_sent,
                                                const void* __restrict__ h_type,
                                                const void* __restrict__ attn_w,
                                                float* __restrict__ s_src,
                                                float* __restrict__ s_dst) {
    int lane = threadIdx.x & 63;
    int r0   = (blockIdx.x * 4 + (int)(threadIdx.x >> 6)) * 16;  // first of 16 rows
    bool isbf = detect_bf16((const uint32_t*)h_sent);
    float v[16];
    if (isbf) {
        uint32_t wv_s = ((const uint32_t*)attn_w)[lane];
        uint32_t wv_t = ((const uint32_t*)attn_w)[64 + lane];
        float ws0 = bf2f(wv_s & 0xffffu), ws1 = bf2f(wv_s >> 16);
        float wt0 = bf2f(wv_t & 0xffffu), wt1 = bf2f(wv_t >> 16);
#pragma unroll
        for (int i = 0; i < 16; i++) {
            int g = r0 + i;
            if (g >= NROWS) { v[i] = 0.0f; continue; }
            bool isSrc = g < N_SENT;
            const uint32_t* hp = isSrc
                ? (const uint32_t*)h_sent + (size_t)g * 64
                : (const uint32_t*)h_type + (size_t)(g - N_SENT) * 64;
            uint32_t hv = hp[lane];
            v[i] = isSrc ? (bf2f(hv & 0xffffu) * ws0 + bf2f(hv >> 16) * ws1)
                         : (bf2f(hv & 0xffffu) * wt0 + bf2f(hv >> 16) * wt1);
        }
    } else {
        float2 wv_s = ((const float2*)attn_w)[lane];
        float2 wv_t = ((const float2*)attn_w)[64 + lane];
#pragma unroll
        for (int i = 0; i < 16; i++) {
            int g = r0 + i;
            if (g >= NROWS) { v[i] = 0.0f; continue; }
            bool isSrc = g < N_SENT;
            const float2* hp = isSrc
                ? (const float2*)h_sent + (size_t)g * 64
                : (const float2*)h_type + (size_t)(g - N_SENT) * 64;
            float2 hv = hp[lane];
            v[i] = isSrc ? (hv.x * wv_s.x + hv.y * wv_s.y)
                         : (hv.x * wv_t.x + hv.y * wv_t.y);
        }
    }
    // fold 16 rows -> 1 value/lane (row = lane&15): merge stages d=1,2,4,8, then butterfly
    int b0 = lane & 1, b1 = (lane >> 1) & 1, b2 = (lane >> 2) & 1, b3 = (lane >> 3) & 1;
    float w_[8];
#pragma unroll
    for (int i = 0; i < 8; i++) {
        float keep = b0 ? v[2 * i + 1] : v[2 * i];
        float send = b0 ? v[2 * i]     : v[2 * i + 1];
        w_[i] = keep + __shfl_xor(send, 1, 64);
    }
    float x_[4];
#pragma unroll
    for (int i = 0; i < 4; i++) {
        float keep = b1 ? w_[2 * i + 1] : w_[2 * i];
        float send = b1 ? w_[2 * i]     : w_[2 * i + 1];
        x_[i] = keep + __shfl_xor(send, 2, 64);
    }
    float y_[2];
#pragma unroll
    for (int i = 0; i < 2; i++) {
        float keep = b2 ? x_[2 * i + 1] : x_[2 * i];
        float send = b2 ? x_[2 * i]     : x_[2 * i + 1];
        y_[i] = keep + __shfl_xor(send, 4, 64);
    }
    float z;
    {
        float keep = b3 ? y_[1] : y_[0];
        float send = b3 ? y_[0] : y_[1];
        z = keep + __shfl_xor(send, 8, 64);
    }
    z += __shfl_xor(z, 16, 64);
    z += __shfl_xor(z, 32, 64);
    if (lane < 16) {
        int g = r0 + lane;
        if (g < NROWS) {
            if (g < N_SENT) s_src[g] = z;
            else            s_dst[g - N_SENT] = z;
        }
    }
}

// ---- count: per-chunk LDS histogram -> plain stores into count2[c][bin] ----
__global__ __launch_bounds__(256) void count_k(const int* __restrict__ dst,
                                               uint32_t* __restrict__ count2) {
    __shared__ uint32_t hist[N_TYPE];   // 40 KB
    int cb = blockIdx.x;                // [0, HB)
    int t  = threadIdx.x;
    for (int i = t; i < N_TYPE; i += 256) hist[i] = 0u;
    __syncthreads();
    int e0 = cb * HCHUNK;
    for (int i = t; i < HCHUNK; i += 256)
        atomicAdd(&hist[dst[e0 + i]], 1u);
    __syncthreads();
    uint32_t* row = count2 + (size_t)cb * N_TYPE;
    for (int i = t; i < N_TYPE; i += 256) row[i] = hist[i];
}

// ---- column exclusive-scan over chunks: count2[c][bin] -> base2 (in place), total[bin] ----
__global__ __launch_bounds__(256) void sumscan_k(uint32_t* __restrict__ count2,
                                                 uint32_t* __restrict__ total) {
    int b = blockIdx.x * 256 + threadIdx.x;   // bin
    if (b >= N_TYPE) return;
    uint32_t run = 0;
#pragma unroll 4
    for (int c = 0; c < HB; c++) {
        uint32_t* p = count2 + (size_t)c * N_TYPE + b;
        uint32_t v = *p;
        *p = run;
        run += v;
    }
    total[b] = run;
}

// ---- single-block exclusive scan of totals -> offsets[N_TYPE+1] ----
__global__ __launch_bounds__(1024) void scan_k(const uint32_t* __restrict__ total,
                                               uint32_t* __restrict__ offsets) {
    const int CH = 10;   // 1024*10 >= N_TYPE
    int t = threadIdx.x, lane = t & 63, wv = t >> 6;   // 16 waves
    int base = t * CH;
    uint32_t local[CH];
    uint32_t tsum = 0;
#pragma unroll
    for (int i = 0; i < CH; i++) {
        int idx = base + i;
        uint32_t c = (idx < N_TYPE) ? total[idx] : 0u;
        local[i] = c;
        tsum += c;
    }
    uint32_t orig = tsum;
#pragma unroll
    for (int off = 1; off < 64; off <<= 1) {
        uint32_t v = __shfl_up(tsum, off, 64);
        if (lane >= off) tsum += v;
    }
    __shared__ uint32_t wsum[16];
    if (lane == 63) wsum[wv] = tsum;
    __syncthreads();
    if (wv == 0 && lane < 16) {
        uint32_t u = wsum[lane], o = u;
#pragma unroll
        for (int off = 1; off < 16; off <<= 1) {
            uint32_t v = __shfl_up(u, off, 64);
            if (lane >= off) u += v;
        }
        wsum[lane] = u - o;   // exclusive wave prefix
    }
    __syncthreads();
    uint32_t run = wsum[wv] + tsum - orig;   // exclusive thread prefix
#pragma unroll
    for (int i = 0; i < CH; i++) {
        int idx = base + i;
        if (idx < N_TYPE) {
            offsets[idx] = run;
            run += local[i];
        } else if (idx == N_TYPE) {
            offsets[idx] = run;   // == NEDGE
        }
    }
}

// ---- fill: LDS cursors = offsets[bin] + base2[c][bin] (plain loads), LDS-atomic scatter ----
__global__ __launch_bounds__(256) void fill_k(const int* __restrict__ src,
                                              const int* __restrict__ dst,
                                              const uint32_t* __restrict__ offsets,
                                              const uint32_t* __restrict__ base2,
                                              uint32_t* __restrict__ edge_src) {
    __shared__ uint32_t cur[N_TYPE];   // 40 KB
    int cb = blockIdx.x;               // [0, HB)
    int t  = threadIdx.x;
    const uint32_t* brow = base2 + (size_t)cb * N_TYPE;
    for (int i = t; i < N_TYPE; i += 256) cur[i] = offsets[i] + brow[i];
    __syncthreads();
    int e0 = cb * HCHUNK;
    for (int i = t; i < HCHUNK; i += 256) {
        int e = e0 + i;
        uint32_t pos = atomicAdd(&cur[dst[e]], 1u);   // LDS-only atomic
        edge_src[pos] = (uint32_t)src[e];
    }
}

// ---- one wave per destination: max -> exp-weighted gather-sum (x8 unrolled) -> normalize
__global__ __launch_bounds__(256) void agg_k(const void* __restrict__ h_sent,
                                             const void* __restrict__ h_type,
                                             const float* __restrict__ s_src,
                                             const float* __restrict__ s_dst,
                                             const uint32_t* __restrict__ offsets,
                                             const uint32_t* __restrict__ edge_src,
                                             void* __restrict__ out) {
    __shared__ float    sc[4][MAXDEG];
    __shared__ uint32_t ss[4][MAXDEG];
    int j     = (blockIdx.x * 256 + threadIdx.x) >> 6;
    int wslot = threadIdx.x >> 6;
    int lane  = threadIdx.x & 63;
    bool valid = j < N_TYPE;
    bool isbf  = detect_bf16((const uint32_t*)h_sent);
    uint32_t beg = 0, deg = 0;
    float sdj = 0.0f;
    if (valid) {
        beg = offsets[j];
        deg = offsets[j + 1] - beg;
        sdj = s_dst[j];
    }
    float*    mysc = sc[wslot];
    uint32_t* myss = ss[wslot];
    bool fits = (deg <= MAXDEG);
    float m = -INFINITY;
    for (uint32_t k = lane; k < deg; k += 64) {
        uint32_t s = edge_src[beg + k];
        float v = s_src[s] + sdj;
        v = v > 0.0f ? v : 0.01f * v;
        if (fits) { mysc[k] = v; myss[k] = s; }
        m = fmaxf(m, v);
    }
#pragma unroll
    for (int off = 32; off; off >>= 1) m = fmaxf(m, __shfl_xor(m, off, 64));
    __syncthreads();   // LDS visibility (uniform: every thread reaches this)
    if (!valid) return;
    if (deg == 0) {    // isolated node keeps its input feature
        if (isbf) ((uint32_t*)out)[(size_t)j * 64 + lane] =
                      ((const uint32_t*)h_type)[(size_t)j * 64 + lane];
        else      ((float2*)out)[(size_t)j * 64 + lane] =
                      ((const float2*)h_type)[(size_t)j * 64 + lane];
        return;
    }
    float denom = 0.0f, a0 = 0.0f, a1 = 0.0f;
    if (isbf) {
        const uint32_t* hp = (const uint32_t*)h_sent;
        uint32_t k = 0;
        if (fits) {
            for (; k + 8 <= deg; k += 8) {
                uint32_t sv[8]; float vv[8]; uint32_t gv[8];
#pragma unroll
                for (int i = 0; i < 8; i++) { sv[i] = myss[k + i]; vv[i] = mysc[k + i]; }
#pragma unroll
                for (int i = 0; i < 8; i++) gv[i] = hp[(size_t)sv[i] * 64 + lane];
#pragma unroll
                for (int i = 0; i < 8; i++) {
                    float w = __expf(vv[i] - m);
                    denom += w;
                    a0 += w * bf2f(gv[i] & 0xffffu);
                    a1 += w * bf2f(gv[i] >> 16);
                }
            }
            for (; k < deg; ++k) {
                float w = __expf(mysc[k] - m);
                uint32_t g = hp[(size_t)myss[k] * 64 + lane];
                denom += w;
                a0 += w * bf2f(g & 0xffffu);
                a1 += w * bf2f(g >> 16);
            }
        } else {
            for (k = 0; k < deg; ++k) {
                uint32_t s = edge_src[beg + k];
                float v = s_src[s] + sdj; v = v > 0.0f ? v : 0.01f * v;
                float w = __expf(v - m);
                uint32_t g = hp[(size_t)s * 64 + lane];
                denom += w;
                a0 += w * bf2f(g & 0xffffu);
                a1 += w * bf2f(g >> 16);
            }
        }
        float inv = 1.0f / denom;
        ((uint32_t*)out)[(size_t)j * 64 + lane] = f2bf(a0 * inv) | (f2bf(a1 * inv) << 16);
    } else {
        const float2* hp = (const float2*)h_sent;
        uint32_t k = 0;
        if (fits) {
            for (; k + 8 <= deg; k += 8) {
                uint32_t sv[8]; float vv[8]; float2 gv[8];
#pragma unroll
                for (int i = 0; i < 8; i++) { sv[i] = myss[k + i]; vv[i] = mysc[k + i]; }
#pragma unroll
                for (int i = 0; i < 8; i++) gv[i] = hp[(size_t)sv[i] * 64 + lane];
#pragma unroll
                for (int i = 0; i < 8; i++) {
                    float w = __expf(vv[i] - m);
                    denom += w;
                    a0 += w * gv[i].x;
                    a1 += w * gv[i].y;
                }
            }
            for (; k < deg; ++k) {
                float w = __expf(mysc[k] - m);
                float2 g = hp[(size_t)myss[k] * 64 + lane];
                denom += w;
                a0 += w * g.x;
                a1 += w * g.y;
            }
        } else {
            for (k = 0; k < deg; ++k) {
                uint32_t s = edge_src[beg + k];
                float v = s_src[s] + sdj; v = v > 0.0f ? v : 0.01f * v;
                float w = __expf(v - m);
                float2 g = hp[(size_t)s * 64 + lane];
                denom += w;
                a0 += w * g.x;
                a1 += w * g.y;
            }
        }
        float inv = 1.0f / denom;
        ((float2*)out)[(size_t)j * 64 + lane] = make_float2(a0 * inv, a1 * inv);
    }
}

static inline size_t align_up(size_t x) { return (x + 255) & ~(size_t)255; }

extern "C" void kernel_launch(void* const* d_in, const int* in_sizes, int n_in,
                              void* d_out, int out_size, void* d_ws, size_t ws_size,
                              hipStream_t stream) {
    const void* h_sent = d_in[0];
    const void* h_type = d_in[1];
    const void* attn_w = d_in[2];
    const int* src_idx = (const int*)d_in[3];
    const int* dst_idx = (const int*)d_in[4];

    char* w = (char*)d_ws;
    float*    s_src     = (float*)w;    w += align_up((size_t)N_SENT * 4);
    float*    s_dst     = (float*)w;    w += align_up((size_t)N_TYPE * 4);
    uint32_t* count2    = (uint32_t*)w; w += align_up((size_t)HB * N_TYPE * 4);  // 2.56 MB
    uint32_t* total     = (uint32_t*)w; w += align_up((size_t)N_TYPE * 4);
    uint32_t* offsets   = (uint32_t*)w; w += align_up((size_t)(N_TYPE + 1) * 4);
    uint32_t* edge_src  = (uint32_t*)w; w += align_up((size_t)NEDGE * 4);
    // total ~5.7 MB

    scores_k<<<SCORE_BLOCKS, 256, 0, stream>>>(h_sent, h_type, attn_w, s_src, s_dst);
    count_k<<<HB, 256, 0, stream>>>(dst_idx, count2);
    sumscan_k<<<(N_TYPE + 255) / 256, 256, 0, stream>>>(count2, total);
    scan_k<<<1, 1024, 0, stream>>>(total, offsets);
    fill_k<<<HB, 256, 0, stream>>>(src_idx, dst_idx, offsets, count2, edge_src);
    agg_k<<<(N_TYPE + 3) / 4, 256, 0, stream>>>(h_sent, h_type, s_src, s_dst,
                                                offsets, edge_src, d_out);
}